// Round 2
// baseline (483.900 us; speedup 1.0000x reference)
//
#include <hip/hip_runtime.h>
#include <cstdint>
#include <cstddef>

#define T_DIM 2048
#define N_DIM 256
#define KMAXC 512      // (T + C) / (C+1), C = 3
#define WPB 4          // waves per block

__device__ __forceinline__ float wave_max_f(float x) {
#pragma unroll
  for (int o = 32; o > 0; o >>= 1) x = fmaxf(x, __shfl_xor(x, o));
  return x;
}
__device__ __forceinline__ float wave_sum_f(float x) {
#pragma unroll
  for (int o = 32; o > 0; o >>= 1) x += __shfl_xor(x, o);
  return x;
}
__device__ __forceinline__ int wave_sum_i(int x) {
#pragma unroll
  for (int o = 32; o > 0; o >>= 1) x += __shfl_xor(x, o);
  return x;
}
__device__ __forceinline__ int wave_min_i(int x) {
#pragma unroll
  for (int o = 32; o > 0; o >>= 1) x = min(x, __shfl_xor(x, o));
  return x;
}
__device__ __forceinline__ int wave_max_i(int x) {
#pragma unroll
  for (int o = 32; o > 0; o >>= 1) x = max(x, __shfl_xor(x, o));
  return x;
}

__global__ __launch_bounds__(WPB * 64)
void stca_kernel(const float* __restrict__ vmem, const int* __restrict__ labels,
                 float* __restrict__ out) {
  __shared__ unsigned long long nib64[WPB][64];     // 512 spike-nibbles per wave
  __shared__ int st_pos[WPB][KMAXC + 1];            // start position of cluster k (+sentinel T)
  __shared__ int spk_before[WPB][KMAXC + 1];        // #spikes strictly before start k (+sentinel total)
  __shared__ float wave_loss[WPB];

  const int lane = threadIdx.x & 63;
  const int w = threadIdx.x >> 6;
  const int r = blockIdx.x * WPB + w;               // trace id = b*N + n
  const int b = r >> 8;                             // N = 256
  const int n = r & (N_DIM - 1);
  const float4* row4 = reinterpret_cast<const float4*>(vmem + (size_t)r * T_DIM);

  // ---- Phase A: coalesced load (1 KB / instruction), interleaved ownership ----
  float4 v[8];
#pragma unroll
  for (int j = 0; j < 8; ++j) v[j] = row4[j * 64 + lane];

  unsigned char* nbytes = reinterpret_cast<unsigned char*>(&nib64[w][0]);
  float vmax = -3.4e38f;
#pragma unroll
  for (int j = 0; j < 8; ++j) {
    vmax = fmaxf(vmax, fmaxf(fmaxf(v[j].x, v[j].y), fmaxf(v[j].z, v[j].w)));
    unsigned nb = (v[j].x >= 0.f ? 1u : 0u) | (v[j].y >= 0.f ? 2u : 0u) |
                  (v[j].z >= 0.f ? 4u : 0u) | (v[j].w >= 0.f ? 8u : 0u);
    nbytes[j * 64 + lane] = (unsigned char)nb;      // nibble for t = (j*64+lane)*4 .. +3
  }
  __syncthreads();

  // ---- Phase B: contiguous bit view — lane owns times [lane*32, lane*32+32) ----
  unsigned long long packed = nib64[w][lane];
  unsigned word = 0;
#pragma unroll
  for (int q = 0; q < 8; ++q)
    word |= (unsigned)((packed >> (8 * q)) & 0xFull) << (4 * q);

  unsigned prev = (unsigned)__shfl_up((int)word, 1);
  if (lane == 0) prev = 0u;
  // blocked[e] = spike at t-1 or t-2 or t-3  (C = 3)
  unsigned blocked = ((word << 1) | (prev >> 31)) |
                     ((word << 2) | (prev >> 30)) |
                     ((word << 3) | (prev >> 29));
  unsigned starts = word & ~blocked;

  // joint inclusive scan of (spike count | start count << 16) across the wave
  int pack = __popc(word) | (__popc(starts) << 16);
  int isc = pack;
#pragma unroll
  for (int off = 1; off < 64; off <<= 1) {
    int y = __shfl_up(isc, off);
    isc += (lane >= off) ? y : 0;
  }
  const int total = __shfl(isc, 63);
  const int excl = isc - pack;
  const int spike_base = excl & 0xFFFF;
  const int cid_base = excl >> 16;
  const int total_spikes = total & 0xFFFF;
  const int num_cluster = total >> 16;

  // per-start stores: cluster k starts at p_k; count_k = spk_before[k+1]-spk_before[k]
  unsigned s = starts;
  int k = cid_base;
  while (s) {
    int e = __builtin_ctz(s);
    st_pos[w][k] = lane * 32 + e;
    spk_before[w][k] = spike_base + __popc(word & ((1u << e) - 1u));
    ++k;
    s &= s - 1;
  }
  if (lane == 0) {
    st_pos[w][num_cluster] = T_DIM;
    spk_before[w][num_cluster] = total_spikes;
  }
  __syncthreads();

  float loss_c = 0.f;
  const float vmax_all = wave_max_f(vmax);
  const bool is_label = (labels[b] == n);

  if (num_cluster > 0) {                            // wave-uniform branch
    // ---- smallest cluster (ties -> lowest k) ----
    int key = 0x7FFFFFFF;
    for (int kk = lane; kk < num_cluster; kk += 64) {
      int cnt = spk_before[w][kk + 1] - spk_before[w][kk];
      key = min(key, (cnt << 10) | kk);             // cnt<=2048, kk<512
    }
    key = wave_min_i(key);
    const int kmin = key & 1023;
    const int fmin = st_pos[w][kmin];
    const int pend = st_pos[w][kmin + 1];

    // ---- last spike in [fmin, pend) ----
    const int lo = lane * 32;
    const int lclip = fmin - lo;
    const int rclip = pend - lo;
    unsigned mlo = (lclip <= 0) ? 0xFFFFFFFFu : ((lclip >= 32) ? 0u : ~((1u << lclip) - 1u));
    unsigned mhi = (rclip >= 32) ? 0xFFFFFFFFu : ((rclip <= 0) ? 0u : ((1u << rclip) - 1u));
    unsigned m = word & mlo & mhi;
    int cand = m ? (lo + 31 - __builtin_clz(m)) : -1;
    const int lmin = wave_max_i(cand);

    // ---- mean of v>0 over [fmin, lmin], values still in registers ----
    float sum = 0.f;
    int cnt = 0;
#pragma unroll
    for (int j = 0; j < 8; ++j) {
      const int tb = (j * 64 + lane) * 4;
      const float vv[4] = {v[j].x, v[j].y, v[j].z, v[j].w};
#pragma unroll
      for (int e = 0; e < 4; ++e) {
        const int t = tb + e;
        const bool in = (t >= fmin) && (t <= lmin) && (vv[e] > 0.f);
        sum += in ? vv[e] : 0.f;
        cnt += in ? 1 : 0;
      }
    }
    sum = wave_sum_f(sum);
    cnt = wave_sum_i(cnt);
    if (!is_label) loss_c = sum / (float)max(cnt, 1);   // false positive
  } else {
    if (is_label) loss_c = -vmax_all;                   // miss
  }

  if (lane == 0) {
    out[1 + r] = (float)num_cluster;                    // spike_output
    wave_loss[w] = loss_c;
  }
  __syncthreads();
  if (threadIdx.x == 0) {
    float bl = wave_loss[0] + wave_loss[1] + wave_loss[2] + wave_loss[3];
    atomicAdd(out, bl);                                 // loss
  }
}

extern "C" void kernel_launch(void* const* d_in, const int* in_sizes, int n_in,
                              void* d_out, int out_size, void* d_ws, size_t ws_size,
                              hipStream_t stream) {
  const float* vmem = (const float*)d_in[0];
  // d_in[1] (vlastmem) is unused by the forward pass — never read it.
  const int* labels = (const int*)d_in[2];
  float* out = (float*)d_out;

  hipMemsetAsync(d_out, 0, sizeof(float), stream);      // zero the loss accumulator

  const int traces = 128 * N_DIM;                        // 32768
  stca_kernel<<<dim3(traces / WPB), dim3(WPB * 64), 0, stream>>>(vmem, labels, out);
}

// Round 3
// 464.048 us; speedup vs baseline: 1.0428x; 1.0428x over previous
//
#include <hip/hip_runtime.h>
#include <cstdint>
#include <cstddef>

#define T_DIM 2048
#define N_DIM 256
#define KMAXC 512      // (T + C) / (C+1), C = 3
#define WPB 4          // waves per block
#define NBLOCKS (128 * N_DIM / WPB)   // 8192

__device__ __forceinline__ float wave_max_f(float x) {
#pragma unroll
  for (int o = 32; o > 0; o >>= 1) x = fmaxf(x, __shfl_xor(x, o));
  return x;
}
__device__ __forceinline__ float wave_sum_f(float x) {
#pragma unroll
  for (int o = 32; o > 0; o >>= 1) x += __shfl_xor(x, o);
  return x;
}
__device__ __forceinline__ int wave_sum_i(int x) {
#pragma unroll
  for (int o = 32; o > 0; o >>= 1) x += __shfl_xor(x, o);
  return x;
}
__device__ __forceinline__ int wave_min_i(int x) {
#pragma unroll
  for (int o = 32; o > 0; o >>= 1) x = min(x, __shfl_xor(x, o));
  return x;
}
__device__ __forceinline__ int wave_max_i(int x) {
#pragma unroll
  for (int o = 32; o > 0; o >>= 1) x = max(x, __shfl_xor(x, o));
  return x;
}

__global__ __launch_bounds__(WPB * 64)
void stca_kernel(const float* __restrict__ vmem, const int* __restrict__ labels,
                 float* __restrict__ out, float* __restrict__ block_loss) {
  __shared__ unsigned long long nib64[WPB][64];     // 512 spike-nibbles per wave
  __shared__ int st_pos[WPB][KMAXC + 1];            // start position of cluster k (+sentinel T)
  __shared__ int spk_before[WPB][KMAXC + 1];        // #spikes strictly before start k (+sentinel total)
  __shared__ float wave_loss[WPB];

  const int lane = threadIdx.x & 63;
  const int w = threadIdx.x >> 6;
  const int r = blockIdx.x * WPB + w;               // trace id = b*N + n
  const int b = r >> 8;                             // N = 256
  const int n = r & (N_DIM - 1);
  const float4* row4 = reinterpret_cast<const float4*>(vmem + (size_t)r * T_DIM);

  // ---- Phase A: coalesced load (1 KB / instruction), interleaved ownership ----
  float4 v[8];
#pragma unroll
  for (int j = 0; j < 8; ++j) v[j] = row4[j * 64 + lane];

  unsigned char* nbytes = reinterpret_cast<unsigned char*>(&nib64[w][0]);
  float vmax = -3.4e38f;
#pragma unroll
  for (int j = 0; j < 8; ++j) {
    vmax = fmaxf(vmax, fmaxf(fmaxf(v[j].x, v[j].y), fmaxf(v[j].z, v[j].w)));
    unsigned nb = (v[j].x >= 0.f ? 1u : 0u) | (v[j].y >= 0.f ? 2u : 0u) |
                  (v[j].z >= 0.f ? 4u : 0u) | (v[j].w >= 0.f ? 8u : 0u);
    nbytes[j * 64 + lane] = (unsigned char)nb;      // nibble for t = (j*64+lane)*4 .. +3
  }
  __syncthreads();

  // ---- Phase B: contiguous bit view — lane owns times [lane*32, lane*32+32) ----
  unsigned long long packed = nib64[w][lane];
  unsigned word = 0;
#pragma unroll
  for (int q = 0; q < 8; ++q)
    word |= (unsigned)((packed >> (8 * q)) & 0xFull) << (4 * q);

  unsigned prev = (unsigned)__shfl_up((int)word, 1);
  if (lane == 0) prev = 0u;
  // blocked[e] = spike at t-1 or t-2 or t-3  (C = 3)
  unsigned blocked = ((word << 1) | (prev >> 31)) |
                     ((word << 2) | (prev >> 30)) |
                     ((word << 3) | (prev >> 29));
  unsigned starts = word & ~blocked;

  // joint inclusive scan of (spike count | start count << 16) across the wave
  int pack = __popc(word) | (__popc(starts) << 16);
  int isc = pack;
#pragma unroll
  for (int off = 1; off < 64; off <<= 1) {
    int y = __shfl_up(isc, off);
    isc += (lane >= off) ? y : 0;
  }
  const int total = __shfl(isc, 63);
  const int excl = isc - pack;
  const int spike_base = excl & 0xFFFF;
  const int cid_base = excl >> 16;
  const int total_spikes = total & 0xFFFF;
  const int num_cluster = total >> 16;

  // per-start stores: cluster k starts at p_k; count_k = spk_before[k+1]-spk_before[k]
  unsigned s = starts;
  int k = cid_base;
  while (s) {
    int e = __builtin_ctz(s);
    st_pos[w][k] = lane * 32 + e;
    spk_before[w][k] = spike_base + __popc(word & ((1u << e) - 1u));
    ++k;
    s &= s - 1;
  }
  if (lane == 0) {
    st_pos[w][num_cluster] = T_DIM;
    spk_before[w][num_cluster] = total_spikes;
  }
  __syncthreads();

  float loss_c = 0.f;
  const float vmax_all = wave_max_f(vmax);
  const bool is_label = (labels[b] == n);

  if (num_cluster > 0) {                            // wave-uniform branch
    // ---- smallest cluster (ties -> lowest k) ----
    int key = 0x7FFFFFFF;
    for (int kk = lane; kk < num_cluster; kk += 64) {
      int cnt = spk_before[w][kk + 1] - spk_before[w][kk];
      key = min(key, (cnt << 10) | kk);             // cnt<=2048, kk<512
    }
    key = wave_min_i(key);
    const int kmin = key & 1023;
    const int fmin = st_pos[w][kmin];
    const int pend = st_pos[w][kmin + 1];

    // ---- last spike in [fmin, pend) ----
    const int lo = lane * 32;
    const int lclip = fmin - lo;
    const int rclip = pend - lo;
    unsigned mlo = (lclip <= 0) ? 0xFFFFFFFFu : ((lclip >= 32) ? 0u : ~((1u << lclip) - 1u));
    unsigned mhi = (rclip >= 32) ? 0xFFFFFFFFu : ((rclip <= 0) ? 0u : ((1u << rclip) - 1u));
    unsigned m = word & mlo & mhi;
    int cand = m ? (lo + 31 - __builtin_clz(m)) : -1;
    const int lmin = wave_max_i(cand);

    // ---- mean of v>0 over [fmin, lmin], values still in registers ----
    float sum = 0.f;
    int cnt = 0;
#pragma unroll
    for (int j = 0; j < 8; ++j) {
      const int tb = (j * 64 + lane) * 4;
      const float vv[4] = {v[j].x, v[j].y, v[j].z, v[j].w};
#pragma unroll
      for (int e = 0; e < 4; ++e) {
        const int t = tb + e;
        const bool in = (t >= fmin) && (t <= lmin) && (vv[e] > 0.f);
        sum += in ? vv[e] : 0.f;
        cnt += in ? 1 : 0;
      }
    }
    sum = wave_sum_f(sum);
    cnt = wave_sum_i(cnt);
    if (!is_label) loss_c = sum / (float)max(cnt, 1);   // false positive
  } else {
    if (is_label) loss_c = -vmax_all;                   // miss
  }

  if (lane == 0) {
    out[1 + r] = (float)num_cluster;                    // spike_output
    wave_loss[w] = loss_c;
  }
  __syncthreads();
  if (threadIdx.x == 0) {
    // no global atomic: per-block partial, reduced by a second kernel.
    block_loss[blockIdx.x] = wave_loss[0] + wave_loss[1] + wave_loss[2] + wave_loss[3];
  }
}

__global__ __launch_bounds__(256)
void reduce_loss_kernel(const float* __restrict__ block_loss, float* __restrict__ out) {
  const int tid = threadIdx.x;
  float s = 0.f;
#pragma unroll
  for (int i = tid; i < NBLOCKS; i += 256) s += block_loss[i];
  __shared__ float part[4];
  s = wave_sum_f(s);
  if ((tid & 63) == 0) part[tid >> 6] = s;
  __syncthreads();
  if (tid == 0) out[0] = part[0] + part[1] + part[2] + part[3];
}

extern "C" void kernel_launch(void* const* d_in, const int* in_sizes, int n_in,
                              void* d_out, int out_size, void* d_ws, size_t ws_size,
                              hipStream_t stream) {
  const float* vmem = (const float*)d_in[0];
  // d_in[1] (vlastmem) is unused by the forward pass — never read it.
  const int* labels = (const int*)d_in[2];
  float* out = (float*)d_out;
  float* block_loss = (float*)d_ws;                     // 8192 floats of scratch

  stca_kernel<<<dim3(NBLOCKS), dim3(WPB * 64), 0, stream>>>(vmem, labels, out, block_loss);
  reduce_loss_kernel<<<dim3(1), dim3(256), 0, stream>>>(block_loss, out);
}

// Round 4
// 457.177 us; speedup vs baseline: 1.0585x; 1.0150x over previous
//
#include <hip/hip_runtime.h>
#include <cstdint>
#include <cstddef>

#define T_DIM 2048
#define N_DIM 256
#define KMAXC 512      // (T + C) / (C+1), C = 3
#define WPB 4          // waves per block
#define NBLOCKS (128 * N_DIM / WPB)   // 8192

__device__ __forceinline__ float wave_max_f(float x) {
#pragma unroll
  for (int o = 32; o > 0; o >>= 1) x = fmaxf(x, __shfl_xor(x, o));
  return x;
}
__device__ __forceinline__ float wave_sum_f(float x) {
#pragma unroll
  for (int o = 32; o > 0; o >>= 1) x += __shfl_xor(x, o);
  return x;
}
__device__ __forceinline__ int wave_sum_i(int x) {
#pragma unroll
  for (int o = 32; o > 0; o >>= 1) x += __shfl_xor(x, o);
  return x;
}
__device__ __forceinline__ int wave_min_i(int x) {
#pragma unroll
  for (int o = 32; o > 0; o >>= 1) x = min(x, __shfl_xor(x, o));
  return x;
}
__device__ __forceinline__ int wave_max_i(int x) {
#pragma unroll
  for (int o = 32; o > 0; o >>= 1) x = max(x, __shfl_xor(x, o));
  return x;
}

__global__ __launch_bounds__(WPB * 64)
void stca_kernel(const float* __restrict__ vmem, const int* __restrict__ labels,
                 float* __restrict__ out, float* __restrict__ block_loss) {
  // All of nib64[w], st_pos[w], spk_before[w] are produced and consumed by
  // wave w only; DS ops from one wave execute in order -> NO __syncthreads
  // needed until the cross-wave wave_loss combine at the end.
  __shared__ unsigned long long nib64[WPB][64];     // 512 spike-nibbles per wave
  __shared__ int st_pos[WPB][KMAXC + 1];            // start position of cluster k (+sentinel T)
  __shared__ int spk_before[WPB][KMAXC + 1];        // #spikes strictly before start k (+sentinel total)
  __shared__ float wave_loss[WPB];

  const int lane = threadIdx.x & 63;
  const int w = threadIdx.x >> 6;
  const int r = blockIdx.x * WPB + w;               // trace id = b*N + n
  const int b = r >> 8;                             // N = 256
  const int n = r & (N_DIM - 1);
  const float4* row4 = reinterpret_cast<const float4*>(vmem + (size_t)r * T_DIM);

  // ---- Phase A: coalesced load (1 KB / instruction), interleaved ownership ----
  float4 v[8];
#pragma unroll
  for (int j = 0; j < 8; ++j) v[j] = row4[j * 64 + lane];

  unsigned char* nbytes = reinterpret_cast<unsigned char*>(&nib64[w][0]);
#pragma unroll
  for (int j = 0; j < 8; ++j) {
    unsigned nb = (v[j].x >= 0.f ? 1u : 0u) | (v[j].y >= 0.f ? 2u : 0u) |
                  (v[j].z >= 0.f ? 4u : 0u) | (v[j].w >= 0.f ? 8u : 0u);
    nbytes[j * 64 + lane] = (unsigned char)nb;      // nibble for t = (j*64+lane)*4 .. +3
  }

  // ---- Phase B: contiguous bit view — lane owns times [lane*32, lane*32+32) ----
  unsigned long long packed = nib64[w][lane];       // same-wave DS, in-order
  unsigned word = 0;
#pragma unroll
  for (int q = 0; q < 8; ++q)
    word |= (unsigned)((packed >> (8 * q)) & 0xFull) << (4 * q);

  unsigned prev = (unsigned)__shfl_up((int)word, 1);
  if (lane == 0) prev = 0u;
  // blocked[e] = spike at t-1 or t-2 or t-3  (C = 3)
  unsigned blocked = ((word << 1) | (prev >> 31)) |
                     ((word << 2) | (prev >> 30)) |
                     ((word << 3) | (prev >> 29));
  unsigned starts = word & ~blocked;

  // joint inclusive scan of (spike count | start count << 16) across the wave
  int pack = __popc(word) | (__popc(starts) << 16);
  int isc = pack;
#pragma unroll
  for (int off = 1; off < 64; off <<= 1) {
    int y = __shfl_up(isc, off);
    isc += (lane >= off) ? y : 0;
  }
  const int total = __shfl(isc, 63);
  const int excl = isc - pack;
  const int spike_base = excl & 0xFFFF;
  const int cid_base = excl >> 16;
  const int total_spikes = total & 0xFFFF;
  const int num_cluster = total >> 16;

  // per-start stores: cluster k starts at p_k; count_k = spk_before[k+1]-spk_before[k]
  unsigned s = starts;
  int k = cid_base;
  while (s) {
    int e = __builtin_ctz(s);
    st_pos[w][k] = lane * 32 + e;
    spk_before[w][k] = spike_base + __popc(word & ((1u << e) - 1u));
    ++k;
    s &= s - 1;
  }
  if (lane == 0) {
    st_pos[w][num_cluster] = T_DIM;
    spk_before[w][num_cluster] = total_spikes;
  }

  float loss_c = 0.f;
  const bool is_label = (labels[b] == n);

  if (num_cluster > 0) {                            // wave-uniform branch
    // ---- smallest cluster (ties -> lowest k) ----
    int key = 0x7FFFFFFF;
    for (int kk = lane; kk < num_cluster; kk += 64) {
      int cnt = spk_before[w][kk + 1] - spk_before[w][kk];
      key = min(key, (cnt << 10) | kk);             // cnt<=2048, kk<512
    }
    key = wave_min_i(key);
    const int kmin = key & 1023;
    const int fmin = st_pos[w][kmin];
    const int pend = st_pos[w][kmin + 1];

    // ---- last spike in [fmin, pend) ----
    const int lo = lane * 32;
    const int lclip = fmin - lo;
    const int rclip = pend - lo;
    unsigned mlo = (lclip <= 0) ? 0xFFFFFFFFu : ((lclip >= 32) ? 0u : ~((1u << lclip) - 1u));
    unsigned mhi = (rclip >= 32) ? 0xFFFFFFFFu : ((rclip <= 0) ? 0u : ((1u << rclip) - 1u));
    unsigned m = word & mlo & mhi;
    int cand = m ? (lo + 31 - __builtin_clz(m)) : -1;
    const int lmin = wave_max_i(cand);

    // hoist wave-uniform span bounds to SGPRs -> scalar group-skip branches
    const int fmin_s = __builtin_amdgcn_readfirstlane(fmin);
    const int lmin_s = __builtin_amdgcn_readfirstlane(lmin);

    // ---- mean of v>0 over [fmin, lmin]; group j covers t in [256j, 256j+256) ----
    float sum = 0.f;
    int cnt = 0;
#pragma unroll
    for (int j = 0; j < 8; ++j) {
      if (lmin_s >= j * 256 && fmin_s < j * 256 + 256) {   // scalar-uniform skip
        const int tb = (j * 64 + lane) * 4;
        const float vv[4] = {v[j].x, v[j].y, v[j].z, v[j].w};
#pragma unroll
        for (int e = 0; e < 4; ++e) {
          const int t = tb + e;
          const bool in = (t >= fmin_s) && (t <= lmin_s) && (vv[e] > 0.f);
          sum += in ? vv[e] : 0.f;
          cnt += in ? 1 : 0;
        }
      }
    }
    sum = wave_sum_f(sum);
    cnt = wave_sum_i(cnt);
    if (!is_label) loss_c = sum / (float)max(cnt, 1);   // false positive
  } else {
    if (is_label) {                                      // miss: -max over full trace
      float vmax = -3.4e38f;
#pragma unroll
      for (int j = 0; j < 8; ++j)
        vmax = fmaxf(vmax, fmaxf(fmaxf(v[j].x, v[j].y), fmaxf(v[j].z, v[j].w)));
      loss_c = -wave_max_f(vmax);
    }
  }

  if (lane == 0) {
    out[1 + r] = (float)num_cluster;                    // spike_output
    wave_loss[w] = loss_c;
  }
  __syncthreads();
  if (threadIdx.x == 0) {
    // no global atomic: per-block partial, reduced by a second kernel.
    block_loss[blockIdx.x] = wave_loss[0] + wave_loss[1] + wave_loss[2] + wave_loss[3];
  }
}

__global__ __launch_bounds__(256)
void reduce_loss_kernel(const float* __restrict__ block_loss, float* __restrict__ out) {
  const int tid = threadIdx.x;
  const float4* bl4 = reinterpret_cast<const float4*>(block_loss);
  float s = 0.f;
#pragma unroll
  for (int i = tid; i < NBLOCKS / 4; i += 256) {
    float4 x = bl4[i];
    s += (x.x + x.y) + (x.z + x.w);
  }
  __shared__ float part[4];
  s = wave_sum_f(s);
  if ((tid & 63) == 0) part[tid >> 6] = s;
  __syncthreads();
  if (tid == 0) out[0] = part[0] + part[1] + part[2] + part[3];
}

extern "C" void kernel_launch(void* const* d_in, const int* in_sizes, int n_in,
                              void* d_out, int out_size, void* d_ws, size_t ws_size,
                              hipStream_t stream) {
  const float* vmem = (const float*)d_in[0];
  // d_in[1] (vlastmem) is unused by the forward pass — never read it.
  const int* labels = (const int*)d_in[2];
  float* out = (float*)d_out;
  float* block_loss = (float*)d_ws;                     // 8192 floats of scratch

  stca_kernel<<<dim3(NBLOCKS), dim3(WPB * 64), 0, stream>>>(vmem, labels, out, block_loss);
  reduce_loss_kernel<<<dim3(1), dim3(256), 0, stream>>>(block_loss, out);
}